// Round 10
// baseline (337.787 us; speedup 1.0000x reference)
//
#include <hip/hip_runtime.h>

#define BB 8
#define NN 2048
#define FIN 256
#define FO 64

typedef short short8_t __attribute__((ext_vector_type(8)));
typedef float float4_t __attribute__((ext_vector_type(4)));

__device__ __forceinline__ unsigned short f2bf(float x) {
  unsigned int u = __float_as_uint(x);
  unsigned int r = (u + 0x7fffu + ((u >> 16) & 1u)) >> 16;
  return (unsigned short)r;
}

#define GLD16(gp, lp)                                                          \
  __builtin_amdgcn_global_load_lds(                                            \
      (const __attribute__((address_space(1))) void*)(gp),                     \
      (__attribute__((address_space(3))) void*)(lp), 16, 0, 0)
#define GLD4(gp, lp)                                                           \
  __builtin_amdgcn_global_load_lds(                                            \
      (const __attribute__((address_space(1))) void*)(gp),                     \
      (__attribute__((address_space(3))) void*)(lp), 4, 0, 0)

// ---------------- K1: Wh = h@W ; f1 ; f2 ; V = Wh*level ; zero scol ---------
__global__ __launch_bounds__(256) void k1_gemm(
    const float* __restrict__ h,
    const float* __restrict__ level,
    const float* __restrict__ W,
    const float* __restrict__ a,
    float* __restrict__ V, float* __restrict__ f1, float* __restrict__ f2,
    float* __restrict__ scol)
{
  __shared__ float wlds[128 * 64];
  __shared__ float hs[16 * 260];
  __shared__ float parts1[16 * 17];
  __shared__ float parts2[16 * 17];
  int t = threadIdx.x;
  int b = blockIdx.x >> 7;
  int i0 = (blockIdx.x & 127) * 16;

  if (blockIdx.x < 64) scol[blockIdx.x * 256 + t] = 0.0f;  // folded k0

  {
    int r_ld = t >> 4, f0 = (t & 15) * 16;
    const float* hp = h + (size_t)(b * NN + i0 + r_ld) * FIN + f0;
    float4 x0 = *(const float4*)(hp);
    float4 x1 = *(const float4*)(hp + 4);
    float4 x2 = *(const float4*)(hp + 8);
    float4 x3 = *(const float4*)(hp + 12);
    float* hd = &hs[r_ld * 260 + f0];
    *(float4*)(hd + 0) = x0; *(float4*)(hd + 4) = x1;
    *(float4*)(hd + 8) = x2; *(float4*)(hd + 12) = x3;
  }

  int r = t >> 4;
  int c4 = (t & 15) * 4;
  float4 acc = {0, 0, 0, 0};

  #pragma unroll
  for (int half = 0; half < 2; ++half) {
    __syncthreads();
    #pragma unroll
    for (int q = 0; q < 8; ++q) {
      int idx = q * 1024 + t * 4;
      *(float4*)&wlds[idx] = *(const float4*)&W[half * 8192 + idx];
    }
    __syncthreads();
    for (int f = 0; f < 128; f += 8) {
      float4 hv0 = *(const float4*)&hs[r * 260 + half * 128 + f];
      float4 hv1 = *(const float4*)&hs[r * 260 + half * 128 + f + 4];
      float hvv[8] = {hv0.x, hv0.y, hv0.z, hv0.w, hv1.x, hv1.y, hv1.z, hv1.w};
      #pragma unroll
      for (int k = 0; k < 8; ++k) {
        float4 wv = *(const float4*)&wlds[(f + k) * 64 + c4];
        acc.x += hvv[k] * wv.x; acc.y += hvv[k] * wv.y;
        acc.z += hvv[k] * wv.z; acc.w += hvv[k] * wv.w;
      }
    }
  }

  float p1 = acc.x * a[c4] + acc.y * a[c4 + 1] + acc.z * a[c4 + 2] + acc.w * a[c4 + 3];
  float p2 = acc.x * a[64 + c4] + acc.y * a[64 + c4 + 1] +
             acc.z * a[64 + c4 + 2] + acc.w * a[64 + c4 + 3];
  parts1[r * 17 + (t & 15)] = p1;
  parts2[r * 17 + (t & 15)] = p2;
  __syncthreads();
  if (t < 16) {
    float s1 = 0.f, s2 = 0.f;
    #pragma unroll
    for (int g = 0; g < 16; ++g) { s1 += parts1[t * 17 + g]; s2 += parts2[t * 17 + g]; }
    f1[b * NN + i0 + t] = s1;
    f2[b * NN + i0 + t] = s2;
  }

  float lv = level[b * NN + i0 + r];
  float4 vv = {acc.x * lv, acc.y * lv, acc.z * lv, acc.w * lv};
  *(float4*)&V[(size_t)(b * NN + i0 + r) * FO + c4] = vv;
}

// ---------------- K2a: column sums + u (row-major, coalesced stores) --------
// (unchanged from round 9 — best known config)
template <int STORE_U>
__global__ __launch_bounds__(512) void k2a_stats(
    const int* __restrict__ adj,
    const float* __restrict__ ntp,
    const float* __restrict__ f1,
    const float* __restrict__ f2,
    unsigned short* __restrict__ u_bf,
    unsigned char* __restrict__ bits,
    float* __restrict__ scol)
{
  __shared__ int ladj[2][16 * 256];   // 32 KB
  __shared__ float lnt[2][16 * 256];  // 32 KB
  __shared__ float red[2048];         // 8 KB
  int t = threadIdx.x;
  int b = blockIdx.x >> 6;
  int row0 = (blockIdx.x & 63) * 32;
  int w = t >> 6, l = t & 63;
  size_t base = (size_t)b * NN;

  auto stage = [&](int buf, int s) {
    int tile = s >> 3, c = s & 7;
    int r0 = row0 + tile * 16 + 2 * w;
    const int* ga = adj + (base + r0) * NN + c * 256 + l * 4;
    const float* gn = ntp + (base + r0) * NN + c * 256 + l * 4;
    GLD16(ga, &ladj[buf][(2 * w) * 256]);
    GLD16(ga + NN, &ladj[buf][(2 * w + 1) * 256]);
    GLD16(gn, &lnt[buf][(2 * w) * 256]);
    GLD16(gn + NN, &lnt[buf][(2 * w + 1) * 256]);
  };

  int jj = t & 255;
  int rh = t >> 8;

  float accJ[8];
  #pragma unroll
  for (int c = 0; c < 8; ++c) accJ[c] = 0.f;
  float f2v[8];
  #pragma unroll
  for (int c = 0; c < 8; ++c) f2v[c] = f2[base + c * 256 + jj];

  stage(0, 0);
  for (int s = 0; s < 16; ++s) {
    int buf = s & 1;
    __syncthreads();
    if (s < 15) stage(buf ^ 1, s + 1);
    int tile = s >> 3, c = s & 7;
    #pragma unroll
    for (int q = 0; q < 8; ++q) {
      int r = rh * 8 + q;
      int av = ladj[buf][r * 256 + jj];
      float nv = lnt[buf][r * 256 + jj];
      float f1v = f1[base + row0 + tile * 16 + r];
      float x = f1v + f2v[c];
      x = fmaxf(x, 0.2f * x);            // leaky_relu slope 0.2
      bool m = av > 0;
      float u = m ? __expf(x * nv) : 0.0f;
      accJ[c] += u;
      if (STORE_U) {
        u_bf[(base + row0 + tile * 16 + r) * NN + c * 256 + jj] = f2bf(u);
      } else {
        unsigned long long bal = __ballot(m);
        if (l == 0)
          *(unsigned long long*)&bits[(base + row0 + tile * 16 + r) * (NN / 8)
                                      + c * 32 + (w & 3) * 8] = bal;
      }
    }
  }

  if (rh == 0) {
    #pragma unroll
    for (int c = 0; c < 8; ++c) red[c * 256 + jj] = accJ[c];
  }
  __syncthreads();
  if (rh == 1) {
    #pragma unroll
    for (int c = 0; c < 8; ++c) red[c * 256 + jj] += accJ[c];
  }
  __syncthreads();
  #pragma unroll
  for (int q = 0; q < 4; ++q)
    atomicAdd(&scol[base + q * 512 + t], red[q * 512 + t]);
}

// ---------------- K2b: pack V'[j][o]=V[j][o]/s_j into MFMA B-frag order -----
__global__ __launch_bounds__(256) void k2b_pack(
    const float* __restrict__ V,
    const float* __restrict__ scol,
    unsigned short* __restrict__ vf)
{
  int t = threadIdx.x;
  int b = blockIdx.x >> 6;
  int kk = blockIdx.x & 63;
  int ng = t >> 6;
  int l = t & 63;
  int jb = kk * 32 + ((l >> 4) * 8);
  int o = ng * 16 + (l & 15);
  unsigned int pk[4];
  #pragma unroll
  for (int p = 0; p < 4; ++p) {
    int jr0 = jb + 2 * p, jr1 = jb + 2 * p + 1;
    float s0 = scol[b * NN + jr0];
    float s1 = scol[b * NN + jr1];
    float i0 = (s0 > 0.f) ? (1.0f / s0) : 0.0f;
    float i1 = (s1 > 0.f) ? (1.0f / s1) : 0.0f;
    float v0 = V[(size_t)(b * NN + jr0) * FO + o] * i0;
    float v1 = V[(size_t)(b * NN + jr1) * FO + o] * i1;
    pk[p] = (unsigned int)f2bf(v0) | ((unsigned int)f2bf(v1) << 16);
  }
  *(uint4*)(vf + (size_t)(((b * 64 + kk) * 4 + ng) * 64 + l) * 8) =
      make_uint4(pk[0], pk[1], pk[2], pk[3]);
}

// ---------------- K3: out = relu(U @ V'), DMA-staged A tiles ----------------
// grid 1024 (8 b x 128 tiles of 16 rows), 256 threads = 4 waves, 4 blk/CU.
// u staged into LDS via global_load_lds width=4 (dense 256-B global bursts),
// row stride 264 shorts (528 B) -> A-frag ds_read_b128 is bank-uniform.
// Wave w stages rows 4w..4w+3 and computes kk_local {2w, 2w+1} per chunk of
// 256 j (8 chunks); vf frags direct from L2 (contiguous 1 KB/instr).
// 4-way cross-wave k-reduce in LDS at the end.
__global__ __launch_bounds__(256) void k3_agg_u5(
    const unsigned short* __restrict__ u_bf,
    const unsigned short* __restrict__ vf,
    float* __restrict__ outp)
{
  __shared__ __align__(16) unsigned short ub[2][16 * 264];  // 16.5 KB
  __shared__ float red[4 * 1088];                           // 17.4 KB
  int t = threadIdx.x;
  int b = blockIdx.x >> 7;
  int tile = blockIdx.x & 127;
  int i0 = tile * 16;
  int w = t >> 6, l = t & 63;
  int col = l & 15, quad = l >> 4;
  size_t ubase = (size_t)(b * NN + i0) * NN;

  auto stage = [&](int buf, int c) {
    #pragma unroll
    for (int r4 = 0; r4 < 4; ++r4) {
      int r = w * 4 + r4;
      const unsigned short* g = u_bf + ubase + (size_t)r * NN + c * 256 + l * 2;
      GLD4(g, &ub[buf][r * 264]);
      GLD4(g + 128, &ub[buf][r * 264 + 128]);
    }
  };

  float4_t acc[4];
  #pragma unroll
  for (int g = 0; g < 4; ++g) acc[g] = (float4_t){0, 0, 0, 0};

  stage(0, 0);
  for (int c = 0; c < 8; ++c) {
    int buf = c & 1;
    __syncthreads();               // DMA(chunk c) drained; buf^1 free
    if (c < 7) stage(buf ^ 1, c + 1);  // prefetch overlaps compute
    #pragma unroll
    for (int s = 0; s < 2; ++s) {
      int kl = w * 2 + s;          // kk_local within chunk (0..7)
      int kk = c * 8 + kl;
      short8_t A = *(const short8_t*)&ub[buf][col * 264 + kl * 32 + quad * 8];
      const unsigned short* vb = vf + (size_t)(b * 64 + kk) * 2048 + l * 8;
      short8_t c0 = *(const short8_t*)(vb);
      short8_t c1 = *(const short8_t*)(vb + 512);
      short8_t c2 = *(const short8_t*)(vb + 1024);
      short8_t c3 = *(const short8_t*)(vb + 1536);
      acc[0] = __builtin_amdgcn_mfma_f32_16x16x32_bf16(A, c0, acc[0], 0, 0, 0);
      acc[1] = __builtin_amdgcn_mfma_f32_16x16x32_bf16(A, c1, acc[1], 0, 0, 0);
      acc[2] = __builtin_amdgcn_mfma_f32_16x16x32_bf16(A, c2, acc[2], 0, 0, 0);
      acc[3] = __builtin_amdgcn_mfma_f32_16x16x32_bf16(A, c3, acc[3], 0, 0, 0);
    }
  }

  #pragma unroll
  for (int r = 0; r < 4; ++r) {
    float* rp = &red[w * 1088 + (quad * 4 + r) * 68 + col];
    rp[0] = acc[0][r];
    rp[16] = acc[1][r];
    rp[32] = acc[2][r];
    rp[48] = acc[3][r];
  }
  __syncthreads();

  int row = t >> 4, o4 = (t & 15) * 4;
  const float* rp = &red[row * 68 + o4];
  float4 s0 = *(const float4*)(rp);
  float4 s1 = *(const float4*)(rp + 1088);
  float4 s2 = *(const float4*)(rp + 2176);
  float4 s3 = *(const float4*)(rp + 3264);
  float4 o;
  o.x = fmaxf(s0.x + s1.x + s2.x + s3.x, 0.0f);
  o.y = fmaxf(s0.y + s1.y + s2.y + s3.y, 0.0f);
  o.z = fmaxf(s0.z + s1.z + s2.z + s3.z, 0.0f);
  o.w = fmaxf(s0.w + s1.w + s2.w + s3.w, 0.0f);
  *(float4*)&outp[(size_t)(b * NN + i0 + row) * FO + o4] = o;
}

// ---------------- K3b: fallback — recompute u from nt/f1/f2/bits -----------
__global__ __launch_bounds__(256) void k3_agg_b(
    const float* __restrict__ ntp,
    const unsigned char* __restrict__ bits,
    const float* __restrict__ f1,
    const float* __restrict__ f2,
    const unsigned short* __restrict__ vf,
    float* __restrict__ outp)
{
  __shared__ float red[4 * 16 * 68];
  int t = threadIdx.x;
  int b = blockIdx.x >> 7;
  int i0 = (blockIdx.x & 127) * 16;
  int w = t >> 6, l = t & 63;
  int col = l & 15, quad = l >> 4;
  int gi = b * NN + i0 + col;
  float f1v = f1[gi];
  const float* ntrow = ntp + (size_t)gi * NN;
  const unsigned char* brow = bits + (size_t)gi * (NN / 8);
  float4_t acc0 = {0, 0, 0, 0}, acc1 = {0, 0, 0, 0}, acc2 = {0, 0, 0, 0}, acc3 = {0, 0, 0, 0};

  for (int s = 0; s < 16; ++s) {
    int kk = w * 16 + s;
    int jq = kk * 32 + quad * 8;
    unsigned int m8 = brow[jq >> 3];
    float4 n0 = *(const float4*)(ntrow + jq);
    float4 n1 = *(const float4*)(ntrow + jq + 4);
    float4 g0 = *(const float4*)(f2 + b * NN + jq);
    float4 g1 = *(const float4*)(f2 + b * NN + jq + 4);
    float f2v[8] = {g0.x, g0.y, g0.z, g0.w, g1.x, g1.y, g1.z, g1.w};
    float ntf[8] = {n0.x, n0.y, n0.z, n0.w, n1.x, n1.y, n1.z, n1.w};
    union { unsigned int u[4]; short8_t v; } A;
    #pragma unroll
    for (int p = 0; p < 4; ++p) {
      int e0 = 2 * p, e1 = 2 * p + 1;
      float x0 = f1v + f2v[e0]; x0 = fmaxf(x0, 0.2f * x0);
      float u0 = ((m8 >> e0) & 1u) ? __expf(x0 * ntf[e0]) : 0.0f;
      float x1 = f1v + f2v[e1]; x1 = fmaxf(x1, 0.2f * x1);
      float u1 = ((m8 >> e1) & 1u) ? __expf(x1 * ntf[e1]) : 0.0f;
      A.u[p] = (unsigned int)f2bf(u0) | ((unsigned int)f2bf(u1) << 16);
    }
    const unsigned short* vb = vf + (size_t)(b * 64 + kk) * 2048 + l * 8;
    short8_t bf0 = *(const short8_t*)(vb);
    short8_t bf1 = *(const short8_t*)(vb + 512);
    short8_t bf2 = *(const short8_t*)(vb + 1024);
    short8_t bf3 = *(const short8_t*)(vb + 1536);
    acc0 = __builtin_amdgcn_mfma_f32_16x16x32_bf16(A.v, bf0, acc0, 0, 0, 0);
    acc1 = __builtin_amdgcn_mfma_f32_16x16x32_bf16(A.v, bf1, acc1, 0, 0, 0);
    acc2 = __builtin_amdgcn_mfma_f32_16x16x32_bf16(A.v, bf2, acc2, 0, 0, 0);
    acc3 = __builtin_amdgcn_mfma_f32_16x16x32_bf16(A.v, bf3, acc3, 0, 0, 0);
  }

  #pragma unroll
  for (int r = 0; r < 4; ++r) {
    int rowi = quad * 4 + r;
    red[w * 1088 + rowi * 68 + 0 + col] = acc0[r];
    red[w * 1088 + rowi * 68 + 16 + col] = acc1[r];
    red[w * 1088 + rowi * 68 + 32 + col] = acc2[r];
    red[w * 1088 + rowi * 68 + 48 + col] = acc3[r];
  }
  __syncthreads();

  int row = t >> 4, o4 = (t & 15) * 4;
  const float* rp = &red[row * 68 + o4];
  float4 s0 = *(const float4*)(rp);
  float4 s1 = *(const float4*)(rp + 1088);
  float4 s2 = *(const float4*)(rp + 2176);
  float4 s3 = *(const float4*)(rp + 3264);
  float4 o;
  o.x = fmaxf(s0.x + s1.x + s2.x + s3.x, 0.0f);
  o.y = fmaxf(s0.y + s1.y + s2.y + s3.y, 0.0f);
  o.z = fmaxf(s0.z + s1.z + s2.z + s3.z, 0.0f);
  o.w = fmaxf(s0.w + s1.w + s2.w + s3.w, 0.0f);
  *(float4*)&outp[(size_t)(b * NN + i0 + row) * FO + o4] = o;
}

extern "C" void kernel_launch(void* const* d_in, const int* in_sizes, int n_in,
                              void* d_out, int out_size, void* d_ws, size_t ws_size,
                              hipStream_t stream) {
  const float* h = (const float*)d_in[0];       // fp32 [B,N,FIN]
  const int* adj = (const int*)d_in[1];         // int32 [B,N,N]
  const float* level = (const float*)d_in[2];   // fp32 [B,N]
  const float* ntm = (const float*)d_in[3];     // fp32 [B,N,N]
  const float* W = (const float*)d_in[4];       // fp32 [FIN,FO]
  const float* a = (const float*)d_in[5];       // fp32 [2*FO,1]
  float* outp = (float*)d_out;

  float* V = (float*)d_ws;                              // 4 MB
  float* f1 = V + (size_t)BB * NN * FO;                 // 64 KB
  float* f2 = f1 + BB * NN;                             // 64 KB
  float* scol = f2 + BB * NN;                           // 64 KB
  unsigned short* vf = (unsigned short*)(scol + BB * NN); // 2 MB
  char* tail = (char*)(vf + (size_t)BB * NN * FO);
  size_t fixed = (size_t)(tail - (char*)d_ws);
  size_t need_u = fixed + (size_t)BB * NN * NN * 2;     // + 67 MB
  bool big = (ws_size >= need_u);

  k1_gemm<<<1024, 256, 0, stream>>>(h, level, W, a, V, f1, f2, scol);
  if (big) {
    unsigned short* u_bf = (unsigned short*)tail;
    k2a_stats<1><<<512, 512, 0, stream>>>(adj, ntm, f1, f2, u_bf, nullptr, scol);
    k2b_pack<<<512, 256, 0, stream>>>(V, scol, vf);
    k3_agg_u5<<<1024, 256, 0, stream>>>(u_bf, vf, outp);
  } else {
    unsigned char* bits = (unsigned char*)tail;         // + 4 MB
    k2a_stats<0><<<512, 512, 0, stream>>>(adj, ntm, f1, f2, nullptr, bits, scol);
    k2b_pack<<<512, 256, 0, stream>>>(V, scol, vf);
    k3_agg_b<<<1024, 256, 0, stream>>>(ntm, bits, f1, f2, vf, outp);
  }
}